// Round 6
// baseline (82.586 us; speedup 1.0000x reference)
//
#include <hip/hip_runtime.h>
#include <hip/hip_bf16.h>
#include <math.h>

// GMFlow pipeline. Round 6: pos table restored (trig revert), attn k-split x2
// with fp32 partials for 2 blocks/CU occupancy. corr stays 32-rows/wave.
#define NB 4
#define NC 128
#define NH 64
#define NW 64
#define NHW 4096
#define SCALE 0.08838834764831845f  // 1/sqrt(128)

typedef short bf16x8 __attribute__((ext_vector_type(8)));
typedef float f32x4 __attribute__((ext_vector_type(4)));

__device__ __forceinline__ unsigned bfbits(float f) {
    unsigned u = __float_as_uint(f);
    return (u + 0x7FFFu + ((u >> 16) & 1u)) >> 16;   // RNE fp32->bf16
}
__device__ __forceinline__ unsigned bfpair(float a, float b) {
    return bfbits(a) | (bfbits(b) << 16);
}

// ---------------- pos embedding table [128][32][32] ----------------
__global__ __launch_bounds__(256) void pos_kernel(float* __restrict__ pos) {
    int idx = blockIdx.x * 256 + threadIdx.x;
    if (idx >= NC * 32 * 32) return;
    int x = idx & 31;
    int y = (idx >> 5) & 31;
    int c = idx >> 10;
    const float twopi = 6.283185307179586f;
    const float denom = 32.0f + 1e-6f;
    int cc = (c < 64) ? c : (c - 64);
    float e = (c < 64) ? (float)(y + 1) : (float)(x + 1);
    e = e * (twopi / denom);
    int k = cc >> 1;
    float arg = e * exp2f(-0.41524101186091903f * (float)k);  // 10000^(-k/32)
    pos[idx] = (cc & 1) ? cosf(arg) : sinf(arg);
}

// ---------------- pack: f+pos -> bf16 layouts ----------------
// grid 512: blk<256 -> f0 -> F0t (SCALE-folded); blk>=256 -> f1 -> Bt, Ktw
// F0t/Bt: [4 b][4096 n][128 c] linear token order
// Ktw:    [16 win][128 c][1024 tok] transposed V (rolled window token order)
__global__ __launch_bounds__(256) void pack_kernel(
        const float* __restrict__ f0, const float* __restrict__ f1,
        const float* __restrict__ pos,
        __hip_bfloat16* __restrict__ F0t, __hip_bfloat16* __restrict__ Bt,
        __hip_bfloat16* __restrict__ Ktw) {
    __shared__ float T[64][129];
    int blk = blockIdx.x;
    const bool isA = blk < 256;
    const float* src = isA ? f0 : f1;
    blk &= 255;
    const int y = blk & 63;
    const int b = blk >> 6;
    const int tid = threadIdx.x;
    const float* s = src + (size_t)b * NC * NHW + y * 64;
    const float sA = isA ? SCALE : 1.0f;   // fold QK^T scale into f0 side
    for (int idx = tid; idx < 64 * NC; idx += 256) {
        const int x = idx & 63, c = idx >> 6;
        T[x][c] = (s[c * NHW + x] + pos[(c << 10) + ((y & 31) << 5) + (x & 31)]) * sA;
    }
    __syncthreads();
    __hip_bfloat16* dst = isA ? F0t : Bt;
    for (int idx = tid; idx < 512; idx += 256) {
        const int x = idx >> 3, c0 = (idx & 7) * 16;
        const float* tr = &T[x][c0];
        uint4 v0, v1;
        v0.x = bfpair(tr[0], tr[1]);   v0.y = bfpair(tr[2], tr[3]);
        v0.z = bfpair(tr[4], tr[5]);   v0.w = bfpair(tr[6], tr[7]);
        v1.x = bfpair(tr[8], tr[9]);   v1.y = bfpair(tr[10], tr[11]);
        v1.z = bfpair(tr[12], tr[13]); v1.w = bfpair(tr[14], tr[15]);
        __hip_bfloat16* row = dst + ((size_t)b * NHW + y * 64 + x) * NC + c0;
        *reinterpret_cast<uint4*>(row) = v0;
        *reinterpret_cast<uint4*>(row + 8) = v1;
    }
    if (!isA) {
        // Ktw: thread (c, wj) writes 32 contiguous tokens of one c-row
        const int yp = (y + 48) & 63;          // rolled row y' = (y-16) mod 64
        const int wi = yp >> 5, ry = yp & 31;
        const int c = tid >> 1;
        const int wj = tid & 1;
        const int win = b * 4 + wi * 2 + wj;
        unsigned up[16];
        #pragma unroll
        for (int pr = 0; pr < 16; ++pr) {
            const int x0 = ((wj << 5) + 2 * pr + 16) & 63;   // even => no wrap inside pair
            up[pr] = bfpair(T[x0][c], T[x0 + 1][c]);
        }
        __hip_bfloat16* krow = Ktw + ((size_t)win * NC + c) * 1024 + ry * 32;
        uint4* uv = reinterpret_cast<uint4*>(up);
        #pragma unroll
        for (int i = 0; i < 4; ++i)
            *reinterpret_cast<uint4*>(krow + i * 8) = uv[i];
    }
}

// ---------------- shifted-window attention on MFMA, k-split x2 ----------------
// grid 512 = 16 win x 16 qt x 2 ks. Each block: 64 q-rows, 8 k-tiles (of 64).
// Emits raw fp32 O-numerator [64][128] + Z[64] partials (softmax is linear,
// no max tracking). 72KB LDS -> 2 blocks/CU -> 2 waves/SIMD.
__global__ __launch_bounds__(256) void attn_mfma_kernel(
        const __hip_bfloat16* __restrict__ F0t,
        const __hip_bfloat16* __restrict__ Bt,
        const __hip_bfloat16* __restrict__ Ktw,
        float* __restrict__ Opart,   // [512 blk][64 row][128 c]
        float* __restrict__ Zpart) { // [512 blk][64 row]
    __shared__ __align__(16) char lds[73728];
    char* KsB = lds;             // 2 x 16384 : K tile [64 m][128 c]
    char* VsB = lds + 32768;     // 2 x 16384 : Vt tile [128 c][64 m]
    char* Pscr = lds + 65536;    // 4 x 2048  : per-wave P transpose scratch
    const int tid = threadIdx.x;
    const int lane = tid & 63;
    const int w = tid >> 6;
    const int l15 = lane & 15;
    const int g = lane >> 4;
    const int blk = blockIdx.x;
    const int ks = blk & 1;
    const int qt = (blk >> 1) & 15;
    const int win = blk >> 5;
    const int b = win >> 2, wi = (win >> 1) & 1, wj = win & 1;

    const char* Btb = (const char*)(Bt + (size_t)b * NHW * NC);
    const char* Vsrc = (const char*)(Ktw + (size_t)win * NC * 1024);

    // Q fragments via roll/window map: tok -> original (yo,xo)
    bf16x8 qf[4];
    {
        const int tok = qt * 64 + w * 16 + l15;
        const int yo = ((wi << 5) + (tok >> 5) + 16) & 63;
        const int xo = ((wj << 5) + (tok & 31) + 16) & 63;
        const __hip_bfloat16* qrow =
            F0t + ((size_t)b * NHW + yo * 64 + xo) * NC + g * 8;
        #pragma unroll
        for (int kk = 0; kk < 4; ++kk)
            qf[kk] = *reinterpret_cast<const bf16x8*>(qrow + kk * 32);
    }

    const int reg_q = (wi ? (qt < 8 ? 1 : 2) : 0) * 3
                    + (wj ? ((w & 1) == 0 ? 1 : 2) : 0);

    auto stageK = [&](int buf, int ktg) {
        char* dst = KsB + buf * 16384;
        #pragma unroll
        for (int it = 0; it < 4; ++it) {
            const int obase = w * 4096 + it * 1024;
            const int row = w * 16 + it * 4 + (lane >> 4);
            const int tok = ktg * 64 + row;
            const int yo = ((wi << 5) + (tok >> 5) + 16) & 63;
            const int xo = ((wj << 5) + (tok & 31) + 16) & 63;
            const char* src = Btb + (yo * 64 + xo) * 256 +
                              (((lane & 15) * 16) ^ ((row & 7) << 4));
            __builtin_amdgcn_global_load_lds(
                (const __attribute__((address_space(1))) void*)src,
                (__attribute__((address_space(3))) void*)(dst + obase), 16, 0, 0);
        }
    };
    auto stageV = [&](int buf, int ktg) {
        char* dst = VsB + buf * 16384;
        #pragma unroll
        for (int it = 0; it < 4; ++it) {
            const int obase = w * 4096 + it * 1024;
            const int o = obase + lane * 16;
            const int crow = o >> 7;
            const int off = o & 127;
            __builtin_amdgcn_global_load_lds(
                (const __attribute__((address_space(1))) void*)(Vsrc + crow * 2048 + ktg * 128 + (off ^ ((crow & 7) << 4))),
                (__attribute__((address_space(3))) void*)(dst + obase), 16, 0, 0);
        }
    };

    f32x4 oacc[8] = {{0,0,0,0},{0,0,0,0},{0,0,0,0},{0,0,0,0},
                     {0,0,0,0},{0,0,0,0},{0,0,0,0},{0,0,0,0}};
    float zacc = 0.f;

    stageK(0, ks * 8); stageV(0, ks * 8);
    __syncthreads();

    for (int kt = 0; kt < 8; ++kt) {
        const int ktg = ks * 8 + kt;
        const int buf = kt & 1;
        if (kt < 7) { stageK(buf ^ 1, ktg + 1); stageV(buf ^ 1, ktg + 1); }

        // S^T[k][q] = K . Q^T
        const char* kb = KsB + buf * 16384;
        f32x4 sacc[4] = {{0,0,0,0},{0,0,0,0},{0,0,0,0},{0,0,0,0}};
        #pragma unroll
        for (int kk = 0; kk < 4; ++kk) {
            #pragma unroll
            for (int msub = 0; msub < 4; ++msub) {
                const int byte = msub * 4096 + l15 * 256 + ((kk * 64 + g * 16) ^ ((l15 & 7) << 4));
                bf16x8 kf = *reinterpret_cast<const bf16x8*>(kb + byte);
                sacc[msub] = __builtin_amdgcn_mfma_f32_16x16x32_bf16(kf, qf[kk], sacc[msub], 0, 0, 0);
            }
        }

        // mask + exp (Q pre-scaled; no max needed) + Z + pack P^T -> A-layout
        const int rk_row = (wi ? (ktg < 8 ? 1 : 2) : 0) * 3;
        char* pw = Pscr + w * 2048;
        #pragma unroll
        for (int msub = 0; msub < 4; ++msub) {
            const int rk = rk_row + (wj ? ((msub & 1) == 0 ? 1 : 2) : 0);
            const bool ok = (rk == reg_q);
            const float p0 = ok ? __expf(sacc[msub][0]) : 0.f;
            const float p1 = ok ? __expf(sacc[msub][1]) : 0.f;
            const float p2 = ok ? __expf(sacc[msub][2]) : 0.f;
            const float p3 = ok ? __expf(sacc[msub][3]) : 0.f;
            zacc += (p0 + p1) + (p2 + p3);
            *reinterpret_cast<unsigned*>(pw + l15 * 128 + ((msub * 32 + g * 8 + 0) ^ ((l15 & 7) << 4))) = bfpair(p0, p1);
            *reinterpret_cast<unsigned*>(pw + l15 * 128 + ((msub * 32 + g * 8 + 4) ^ ((l15 & 7) << 4))) = bfpair(p2, p3);
        }
        bf16x8 pf[2];
        #pragma unroll
        for (int kk = 0; kk < 2; ++kk)
            pf[kk] = *reinterpret_cast<const bf16x8*>(pw + l15 * 128 + ((kk * 64 + g * 16) ^ ((l15 & 7) << 4)));

        // O[q][c] += P . V
        const char* vb = VsB + buf * 16384;
        #pragma unroll
        for (int kk = 0; kk < 2; ++kk) {
            #pragma unroll
            for (int co = 0; co < 8; ++co) {
                const int byte = (co * 16 + l15) * 128 + ((kk * 64 + g * 16) ^ ((l15 & 7) << 4));
                bf16x8 vf = *reinterpret_cast<const bf16x8*>(vb + byte);
                oacc[co] = __builtin_amdgcn_mfma_f32_16x16x32_bf16(pf[kk], vf, oacc[co], 0, 0, 0);
            }
        }
        __syncthreads();
    }

    // Z partial: reduce k-quarters (q = l15 per lane)
    float z = zacc;
    z += __shfl_xor(z, 16);
    z += __shfl_xor(z, 32);

    // stage O fp32 in per-wave LDS chunk, then coalesced float4 partial write
    float* of = reinterpret_cast<float*>(lds + w * 8192);
    #pragma unroll
    for (int r = 0; r < 4; ++r) {
        #pragma unroll
        for (int co = 0; co < 8; ++co)
            of[(g * 4 + r) * 128 + co * 16 + l15] = oacc[co][r];
    }
    const size_t obase = ((size_t)blk * 64 + w * 16) * 128;
    #pragma unroll
    for (int j = 0; j < 8; ++j) {
        const int flat = j * 256 + lane * 4;
        *reinterpret_cast<float4*>(&Opart[obase + flat]) =
            *reinterpret_cast<const float4*>(&of[flat]);
    }
    if (lane < 16) Zpart[blk * 64 + w * 16 + lane] = z;
}

// ---------------- attn finalize: combine 2 k-halves -> bf16 At ----------------
// thread t = win*1024 + tok; At pre-scaled by SCALE for the correlation.
__global__ __launch_bounds__(256) void attn_fin_kernel(
        const float* __restrict__ Opart, const float* __restrict__ Zpart,
        __hip_bfloat16* __restrict__ At) {
    const int t = blockIdx.x * 256 + threadIdx.x;
    if (t >= 16 * 1024) return;
    const int win = t >> 10, tok = t & 1023;
    const int qt = tok >> 6, rowloc = tok & 63;
    const int blk0 = win * 32 + qt * 2;
    const float z = Zpart[blk0 * 64 + rowloc] + Zpart[(blk0 + 1) * 64 + rowloc];
    const float zi = SCALE / z;
    const float4* o0 = reinterpret_cast<const float4*>(Opart + ((size_t)blk0 * 64 + rowloc) * 128);
    const float4* o1 = o0 + (64 * 128 / 4);
    const int b = win >> 2, wi = (win >> 1) & 1, wj = win & 1;
    const int yo = ((wi << 5) + (tok >> 5) + 16) & 63;
    const int xo = ((wj << 5) + (tok & 31) + 16) & 63;
    __hip_bfloat16* arow = At + ((size_t)b * NHW + yo * 64 + xo) * NC;
    #pragma unroll
    for (int i = 0; i < 16; ++i) {
        float4 a = o0[i * 2], b4 = o0[i * 2 + 1];
        float4 c = o1[i * 2], d4 = o1[i * 2 + 1];
        uint4 v;
        v.x = bfpair((a.x + c.x) * zi, (a.y + c.y) * zi);
        v.y = bfpair((a.z + c.z) * zi, (a.w + c.w) * zi);
        v.z = bfpair((b4.x + d4.x) * zi, (b4.y + d4.y) * zi);
        v.w = bfpair((b4.z + d4.z) * zi, (b4.w + d4.w) * zi);
        *reinterpret_cast<uint4*>(arow + i * 8) = v;
    }
}

// ---------------- correlation partials: 32 rows/wave, m-split x8 ----------------
// grid 1024 = 4 b x 32 nt(128 rows) x 8 ms. Wave: 2 A-sets share each B-frag read.
__global__ __launch_bounds__(256) void corr_part_kernel(
        const __hip_bfloat16* __restrict__ At,  // [4][4096][128], pre-scaled
        const __hip_bfloat16* __restrict__ Bt,  // [4][4096][128]
        float4* __restrict__ part) {            // [4][4096][8 ms]
    __shared__ __hip_bfloat16 Bs[2][64 * 128];
    const int tid = threadIdx.x;
    const int lane = tid & 63;
    const int w = tid >> 6;
    const int blk = blockIdx.x;
    const int ms = blk & 7;
    const int nt = (blk >> 3) & 31;
    const int b = blk >> 8;
    const int l15 = lane & 15;
    const int g = lane >> 4;
    const int n0 = nt * 128 + w * 32;      // this wave's 32 rows

    const __hip_bfloat16* Ab = At + (size_t)b * NHW * NC;
    const __hip_bfloat16* Bb = Bt + (size_t)b * NHW * NC;

    bf16x8 afrag[2][4];
    #pragma unroll
    for (int s = 0; s < 2; ++s) {
        const __hip_bfloat16* arow = Ab + (size_t)(n0 + s * 16 + l15) * NC + g * 8;
        #pragma unroll
        for (int kk = 0; kk < 4; ++kk)
            afrag[s][kk] = *reinterpret_cast<const bf16x8*>(arow + kk * 32);
    }

    auto stage = [&](int buf, int mtile) {
        const char* srcbase = reinterpret_cast<const char*>(Bb + (size_t)mtile * 64 * NC);
        #pragma unroll
        for (int it = 0; it < 4; ++it) {
            const int obase = w * 4096 + it * 1024;
            const int o = obase + lane * 16;
            const int row = o >> 8;
            const int off = o & 255;
            const char* src = srcbase + row * 256 + (off ^ ((row & 7) << 4));
            __builtin_amdgcn_global_load_lds(
                (const __attribute__((address_space(1))) void*)src,
                (__attribute__((address_space(3))) void*)((char*)&Bs[buf][0] + obase),
                16, 0, 0);
        }
    };

    f32x4 rl[2] = {{0,0,0,0},{0,0,0,0}};
    f32x4 rsm[2] = {{0,0,0,0},{0,0,0,0}};
    f32x4 rsy[2] = {{0,0,0,0},{0,0,0,0}};

    stage(0, ms * 8);
    __syncthreads();

    for (int mt = 0; mt < 8; ++mt) {
        const int buf = mt & 1;
        if (mt < 7) stage(buf ^ 1, ms * 8 + mt + 1);

        f32x4 acc[2][4] = {{{0,0,0,0},{0,0,0,0},{0,0,0,0},{0,0,0,0}},
                           {{0,0,0,0},{0,0,0,0},{0,0,0,0},{0,0,0,0}}};
        const char* base = (const char*)&Bs[buf][0];
        #pragma unroll
        for (int kk = 0; kk < 4; ++kk) {
            #pragma unroll
            for (int msub = 0; msub < 4; ++msub) {
                const int byte = msub * 4096 + l15 * 256 +
                                 ((kk * 64 + g * 16) ^ ((l15 & 7) << 4));
                bf16x8 bfrag = *reinterpret_cast<const bf16x8*>(base + byte);
                acc[0][msub] = __builtin_amdgcn_mfma_f32_16x16x32_bf16(
                    afrag[0][kk], bfrag, acc[0][msub], 0, 0, 0);
                acc[1][msub] = __builtin_amdgcn_mfma_f32_16x16x32_bf16(
                    afrag[1][kk], bfrag, acc[1][msub], 0, 0, 0);
            }
        }
        const float y0 = (float)(ms * 8 + mt);   // m>>6 constant per aligned 64-tile
        #pragma unroll
        for (int s = 0; s < 2; ++s) {
            #pragma unroll
            for (int r = 0; r < 4; ++r) {
                float p0 = __expf(acc[s][0][r]);   // A pre-scaled by SCALE
                float p1 = __expf(acc[s][1][r]);
                float p2 = __expf(acc[s][2][r]);
                float p3 = __expf(acc[s][3][r]);
                float ts = (p0 + p1) + (p2 + p3);
                rl[s][r]  += ts;
                rsy[s][r] += y0 * ts;
                rsm[s][r] += fmaf(3.f, p3, fmaf(2.f, p2, p1));  // x = l15 + 16*msub
            }
        }
        __syncthreads();
    }

    const float xl = (float)l15;
    #pragma unroll
    for (int s = 0; s < 2; ++s) {
        #pragma unroll
        for (int r = 0; r < 4; ++r) {
            float a  = rl[s][r];
            float sx = xl * rl[s][r] + 16.f * rsm[s][r];
            float sy = rsy[s][r];
            #pragma unroll
            for (int m = 1; m < 16; m <<= 1) {
                a  += __shfl_xor(a, m);
                sx += __shfl_xor(sx, m);
                sy += __shfl_xor(sy, m);
            }
            if (l15 == 0) {
                const int n = n0 + s * 16 + g * 4 + r;
                part[((size_t)b * NHW + n) * 8 + ms] = make_float4(a, sx, sy, 0.f);
            }
        }
    }
}

// ---------------- finalize: combine 8 partials, emit flow ----------------
__global__ __launch_bounds__(256) void finalize_kernel(
        const float4* __restrict__ part, float* __restrict__ out) {
    const int idx = blockIdx.x * 256 + threadIdx.x;   // 0..16383 = b*4096+n
    if (idx >= NB * NHW) return;
    const int n = idx & (NHW - 1);
    const int b = idx >> 12;
    float l = 0.f, sx = 0.f, sy = 0.f;
    #pragma unroll
    for (int i = 0; i < 8; ++i) {
        float4 p = part[(size_t)idx * 8 + i];
        l += p.x; sx += p.y; sy += p.z;
    }
    const float inv = 1.0f / l;
    out[(size_t)b * 2 * NHW + n]       = sx * inv - (float)(n & 63);
    out[(size_t)b * 2 * NHW + NHW + n] = sy * inv - (float)(n >> 6);
}

extern "C" void kernel_launch(void* const* d_in, const int* in_sizes, int n_in,
                              void* d_out, int out_size, void* d_ws, size_t ws_size,
                              hipStream_t stream) {
    const float* f0 = (const float*)d_in[0];
    const float* f1 = (const float*)d_in[1];
    float* pos = (float*)d_ws;                               // 512 KB
    __hip_bfloat16* F0t = (__hip_bfloat16*)(pos + 131072);   // 4 MB
    __hip_bfloat16* Bt  = F0t + (size_t)NB * NHW * NC;       // 4 MB
    __hip_bfloat16* Ktw = Bt  + (size_t)NB * NHW * NC;       // 4 MB
    __hip_bfloat16* At  = Ktw + (size_t)16 * NC * 1024;      // 4 MB
    float4* part = (float4*)(At + (size_t)NB * NHW * NC);    // 2 MB
    float* Opart = (float*)(part + (size_t)NB * NHW * 8);    // 16.8 MB
    float* Zpart = Opart + (size_t)512 * 64 * 128;           // 128 KB
    float* out = (float*)d_out;

    pos_kernel<<<512, 256, 0, stream>>>(pos);
    pack_kernel<<<512, 256, 0, stream>>>(f0, f1, pos, F0t, Bt, Ktw);
    attn_mfma_kernel<<<512, 256, 0, stream>>>(F0t, Bt, Ktw, Opart, Zpart);
    attn_fin_kernel<<<64, 256, 0, stream>>>(Opart, Zpart, At);
    corr_part_kernel<<<1024, 256, 0, stream>>>(At, Bt, part);
    finalize_kernel<<<64, 256, 0, stream>>>(part, out);
}

// Round 7
// 70.957 us; speedup vs baseline: 1.1639x; 1.1639x over previous
//
#include <hip/hip_runtime.h>
#include <hip/hip_bf16.h>
#include <math.h>

// GMFlow pipeline. Round 7: attn reverted to fused r5 structure (k-split removed);
// corr upgraded to 64 rows/wave (4 A-sets) to halve LDS-read amplification.
#define NB 4
#define NC 128
#define NH 64
#define NW 64
#define NHW 4096
#define SCALE 0.08838834764831845f  // 1/sqrt(128)

typedef short bf16x8 __attribute__((ext_vector_type(8)));
typedef float f32x4 __attribute__((ext_vector_type(4)));

__device__ __forceinline__ unsigned bfbits(float f) {
    unsigned u = __float_as_uint(f);
    return (u + 0x7FFFu + ((u >> 16) & 1u)) >> 16;   // RNE fp32->bf16
}
__device__ __forceinline__ unsigned bfpair(float a, float b) {
    return bfbits(a) | (bfbits(b) << 16);
}

// ---------------- pos embedding table [128][32][32] ----------------
__global__ __launch_bounds__(256) void pos_kernel(float* __restrict__ pos) {
    int idx = blockIdx.x * 256 + threadIdx.x;
    if (idx >= NC * 32 * 32) return;
    int x = idx & 31;
    int y = (idx >> 5) & 31;
    int c = idx >> 10;
    const float twopi = 6.283185307179586f;
    const float denom = 32.0f + 1e-6f;
    int cc = (c < 64) ? c : (c - 64);
    float e = (c < 64) ? (float)(y + 1) : (float)(x + 1);
    e = e * (twopi / denom);
    int k = cc >> 1;
    float arg = e * exp2f(-0.41524101186091903f * (float)k);  // 10000^(-k/32)
    pos[idx] = (cc & 1) ? cosf(arg) : sinf(arg);
}

// ---------------- pack: f+pos -> bf16 layouts ----------------
// grid 512: blk<256 -> f0 -> F0t (SCALE-folded); blk>=256 -> f1 -> Bt, Ktw
// F0t/Bt: [4 b][4096 n][128 c] linear token order
// Ktw:    [16 win][128 c][1024 tok] transposed V (rolled window token order)
__global__ __launch_bounds__(256) void pack_kernel(
        const float* __restrict__ f0, const float* __restrict__ f1,
        const float* __restrict__ pos,
        __hip_bfloat16* __restrict__ F0t, __hip_bfloat16* __restrict__ Bt,
        __hip_bfloat16* __restrict__ Ktw) {
    __shared__ float T[64][129];
    int blk = blockIdx.x;
    const bool isA = blk < 256;
    const float* src = isA ? f0 : f1;
    blk &= 255;
    const int y = blk & 63;
    const int b = blk >> 6;
    const int tid = threadIdx.x;
    const float* s = src + (size_t)b * NC * NHW + y * 64;
    const float sA = isA ? SCALE : 1.0f;   // fold QK^T scale into f0 side
    for (int idx = tid; idx < 64 * NC; idx += 256) {
        const int x = idx & 63, c = idx >> 6;
        T[x][c] = (s[c * NHW + x] + pos[(c << 10) + ((y & 31) << 5) + (x & 31)]) * sA;
    }
    __syncthreads();
    __hip_bfloat16* dst = isA ? F0t : Bt;
    for (int idx = tid; idx < 512; idx += 256) {
        const int x = idx >> 3, c0 = (idx & 7) * 16;
        const float* tr = &T[x][c0];
        uint4 v0, v1;
        v0.x = bfpair(tr[0], tr[1]);   v0.y = bfpair(tr[2], tr[3]);
        v0.z = bfpair(tr[4], tr[5]);   v0.w = bfpair(tr[6], tr[7]);
        v1.x = bfpair(tr[8], tr[9]);   v1.y = bfpair(tr[10], tr[11]);
        v1.z = bfpair(tr[12], tr[13]); v1.w = bfpair(tr[14], tr[15]);
        __hip_bfloat16* row = dst + ((size_t)b * NHW + y * 64 + x) * NC + c0;
        *reinterpret_cast<uint4*>(row) = v0;
        *reinterpret_cast<uint4*>(row + 8) = v1;
    }
    if (!isA) {
        // Ktw: thread (c, wj) writes 32 contiguous tokens of one c-row
        const int yp = (y + 48) & 63;          // rolled row y' = (y-16) mod 64
        const int wi = yp >> 5, ry = yp & 31;
        const int c = tid >> 1;
        const int wj = tid & 1;
        const int win = b * 4 + wi * 2 + wj;
        unsigned up[16];
        #pragma unroll
        for (int pr = 0; pr < 16; ++pr) {
            const int x0 = ((wj << 5) + 2 * pr + 16) & 63;   // even => no wrap inside pair
            up[pr] = bfpair(T[x0][c], T[x0 + 1][c]);
        }
        __hip_bfloat16* krow = Ktw + ((size_t)win * NC + c) * 1024 + ry * 32;
        uint4* uv = reinterpret_cast<uint4*>(up);
        #pragma unroll
        for (int i = 0; i < 4; ++i)
            *reinterpret_cast<uint4*>(krow + i * 8) = uv[i];
    }
}

// ---------------- shifted-window attention on MFMA (fused, grid 256) ----------------
// 16 win x 16 q-tiles(64 rows). Q from F0t, K gathered from Bt, V from Ktw.
// Output At = softmax(QK^T+mask)V, pre-scaled by SCALE.
__global__ __launch_bounds__(256) void attn_mfma_kernel(
        const __hip_bfloat16* __restrict__ F0t,
        const __hip_bfloat16* __restrict__ Bt,
        const __hip_bfloat16* __restrict__ Ktw,
        __hip_bfloat16* __restrict__ At) {
    __shared__ __align__(16) char lds[73728];
    char* KsB = lds;             // 2 x 16384 : K tile [64 m][128 c]
    char* VsB = lds + 32768;     // 2 x 16384 : Vt tile [128 c][64 m]
    char* Pscr = lds + 65536;    // 4 x 2048  : per-wave P transpose scratch
    const int tid = threadIdx.x;
    const int lane = tid & 63;
    const int w = tid >> 6;
    const int l15 = lane & 15;
    const int g = lane >> 4;
    const int blk = blockIdx.x;
    const int win = blk >> 4;
    const int qt = blk & 15;
    const int b = win >> 2, wi = (win >> 1) & 1, wj = win & 1;

    const char* Btb = (const char*)(Bt + (size_t)b * NHW * NC);
    const char* Vsrc = (const char*)(Ktw + (size_t)win * NC * 1024);

    // Q fragments via roll/window map: tok -> original (yo,xo)
    bf16x8 qf[4];
    {
        const int tok = qt * 64 + w * 16 + l15;
        const int yo = ((wi << 5) + (tok >> 5) + 16) & 63;
        const int xo = ((wj << 5) + (tok & 31) + 16) & 63;
        const __hip_bfloat16* qrow =
            F0t + ((size_t)b * NHW + yo * 64 + xo) * NC + g * 8;
        #pragma unroll
        for (int kk = 0; kk < 4; ++kk)
            qf[kk] = *reinterpret_cast<const bf16x8*>(qrow + kk * 32);
    }

    const int reg_q = (wi ? (qt < 8 ? 1 : 2) : 0) * 3
                    + (wj ? ((w & 1) == 0 ? 1 : 2) : 0);

    auto stageK = [&](int buf, int kt) {
        char* dst = KsB + buf * 16384;
        #pragma unroll
        for (int it = 0; it < 4; ++it) {
            const int obase = w * 4096 + it * 1024;
            const int row = w * 16 + it * 4 + (lane >> 4);
            const int tok = kt * 64 + row;
            const int yo = ((wi << 5) + (tok >> 5) + 16) & 63;
            const int xo = ((wj << 5) + (tok & 31) + 16) & 63;
            const char* src = Btb + (yo * 64 + xo) * 256 +
                              (((lane & 15) * 16) ^ ((row & 7) << 4));
            __builtin_amdgcn_global_load_lds(
                (const __attribute__((address_space(1))) void*)src,
                (__attribute__((address_space(3))) void*)(dst + obase), 16, 0, 0);
        }
    };
    auto stageV = [&](int buf, int kt) {
        char* dst = VsB + buf * 16384;
        #pragma unroll
        for (int it = 0; it < 4; ++it) {
            const int obase = w * 4096 + it * 1024;
            const int o = obase + lane * 16;
            const int crow = o >> 7;
            const int off = o & 127;
            __builtin_amdgcn_global_load_lds(
                (const __attribute__((address_space(1))) void*)(Vsrc + crow * 2048 + kt * 128 + (off ^ ((crow & 7) << 4))),
                (__attribute__((address_space(3))) void*)(dst + obase), 16, 0, 0);
        }
    };

    f32x4 oacc[8] = {{0,0,0,0},{0,0,0,0},{0,0,0,0},{0,0,0,0},
                     {0,0,0,0},{0,0,0,0},{0,0,0,0},{0,0,0,0}};
    float zacc = 0.f;

    stageK(0, 0); stageV(0, 0);
    __syncthreads();

    for (int kt = 0; kt < 16; ++kt) {
        const int buf = kt & 1;
        if (kt < 15) { stageK(buf ^ 1, kt + 1); stageV(buf ^ 1, kt + 1); }

        // S^T[k][q] = K . Q^T
        const char* kb = KsB + buf * 16384;
        f32x4 sacc[4] = {{0,0,0,0},{0,0,0,0},{0,0,0,0},{0,0,0,0}};
        #pragma unroll
        for (int kk = 0; kk < 4; ++kk) {
            #pragma unroll
            for (int msub = 0; msub < 4; ++msub) {
                const int byte = msub * 4096 + l15 * 256 + ((kk * 64 + g * 16) ^ ((l15 & 7) << 4));
                bf16x8 kf = *reinterpret_cast<const bf16x8*>(kb + byte);
                sacc[msub] = __builtin_amdgcn_mfma_f32_16x16x32_bf16(kf, qf[kk], sacc[msub], 0, 0, 0);
            }
        }

        // mask + exp (Q pre-scaled; no max needed) + Z + pack P^T -> A-layout
        const int rk_row = (wi ? (kt < 8 ? 1 : 2) : 0) * 3;
        char* pw = Pscr + w * 2048;
        #pragma unroll
        for (int msub = 0; msub < 4; ++msub) {
            const int rk = rk_row + (wj ? ((msub & 1) == 0 ? 1 : 2) : 0);
            const bool ok = (rk == reg_q);
            const float p0 = ok ? __expf(sacc[msub][0]) : 0.f;
            const float p1 = ok ? __expf(sacc[msub][1]) : 0.f;
            const float p2 = ok ? __expf(sacc[msub][2]) : 0.f;
            const float p3 = ok ? __expf(sacc[msub][3]) : 0.f;
            zacc += (p0 + p1) + (p2 + p3);
            *reinterpret_cast<unsigned*>(pw + l15 * 128 + ((msub * 32 + g * 8 + 0) ^ ((l15 & 7) << 4))) = bfpair(p0, p1);
            *reinterpret_cast<unsigned*>(pw + l15 * 128 + ((msub * 32 + g * 8 + 4) ^ ((l15 & 7) << 4))) = bfpair(p2, p3);
        }
        bf16x8 pf[2];
        #pragma unroll
        for (int kk = 0; kk < 2; ++kk)
            pf[kk] = *reinterpret_cast<const bf16x8*>(pw + l15 * 128 + ((kk * 64 + g * 16) ^ ((l15 & 7) << 4)));

        // O[q][c] += P . V
        const char* vb = VsB + buf * 16384;
        #pragma unroll
        for (int kk = 0; kk < 2; ++kk) {
            #pragma unroll
            for (int co = 0; co < 8; ++co) {
                const int byte = (co * 16 + l15) * 128 + ((kk * 64 + g * 16) ^ ((l15 & 7) << 4));
                bf16x8 vf = *reinterpret_cast<const bf16x8*>(vb + byte);
                oacc[co] = __builtin_amdgcn_mfma_f32_16x16x32_bf16(pf[kk], vf, oacc[co], 0, 0, 0);
            }
        }
        __syncthreads();
    }

    float z = zacc;
    z += __shfl_xor(z, 16);
    z += __shfl_xor(z, 32);

    // normalize (pre-scale by SCALE for the downstream correlation)
    unsigned short* olds = reinterpret_cast<unsigned short*>(lds + w * 4096);
    #pragma unroll
    for (int r = 0; r < 4; ++r) {
        const float zi = SCALE / __shfl(z, g * 4 + r);
        #pragma unroll
        for (int co = 0; co < 8; ++co)
            olds[(g * 4 + r) * 128 + co * 16 + l15] = (unsigned short)bfbits(oacc[co][r] * zi);
    }

    const int qloc = lane >> 2;
    const int c0 = (lane & 3) * 32;
    const int tok = qt * 64 + w * 16 + qloc;
    const int yo = ((wi << 5) + (tok >> 5) + 16) & 63;
    const int xo = ((wj << 5) + (tok & 31) + 16) & 63;
    __hip_bfloat16* arow = At + ((size_t)b * NHW + yo * 64 + xo) * NC + c0;
    #pragma unroll
    for (int i = 0; i < 4; ++i) {
        int4 v = *reinterpret_cast<const int4*>(olds + qloc * 128 + c0 + i * 8);
        *reinterpret_cast<int4*>(arow + i * 8) = v;
    }
}

// ---------------- correlation partials: 64 rows/wave (4 A-sets), m-split x8 ----------------
// grid 512 = 4 b x 16 nt(256 rows) x 8 ms. Each wave owns 64 q-rows; each B-frag
// ds_read feeds 4 MFMAs -> LDS-read amplification halved vs 2 sets.
__global__ __launch_bounds__(256, 2) void corr_part_kernel(
        const __hip_bfloat16* __restrict__ At,  // [4][4096][128], pre-scaled
        const __hip_bfloat16* __restrict__ Bt,  // [4][4096][128]
        float4* __restrict__ part) {            // [4][4096][8 ms]
    __shared__ __hip_bfloat16 Bs[2][64 * 128];
    const int tid = threadIdx.x;
    const int lane = tid & 63;
    const int w = tid >> 6;
    const int blk = blockIdx.x;
    const int ms = blk & 7;
    const int nt = (blk >> 3) & 15;
    const int b = blk >> 7;
    const int l15 = lane & 15;
    const int g = lane >> 4;
    const int n0 = nt * 256 + w * 64;      // this wave's 64 rows

    const __hip_bfloat16* Ab = At + (size_t)b * NHW * NC;
    const __hip_bfloat16* Bb = Bt + (size_t)b * NHW * NC;

    bf16x8 afrag[4][4];
    #pragma unroll
    for (int s = 0; s < 4; ++s) {
        const __hip_bfloat16* arow = Ab + (size_t)(n0 + s * 16 + l15) * NC + g * 8;
        #pragma unroll
        for (int kk = 0; kk < 4; ++kk)
            afrag[s][kk] = *reinterpret_cast<const bf16x8*>(arow + kk * 32);
    }

    auto stage = [&](int buf, int mtile) {
        const char* srcbase = reinterpret_cast<const char*>(Bb + (size_t)mtile * 64 * NC);
        #pragma unroll
        for (int it = 0; it < 4; ++it) {
            const int obase = w * 4096 + it * 1024;
            const int o = obase + lane * 16;
            const int row = o >> 8;
            const int off = o & 255;
            const char* src = srcbase + row * 256 + (off ^ ((row & 7) << 4));
            __builtin_amdgcn_global_load_lds(
                (const __attribute__((address_space(1))) void*)src,
                (__attribute__((address_space(3))) void*)((char*)&Bs[buf][0] + obase),
                16, 0, 0);
        }
    };

    f32x4 rl[4]  = {{0,0,0,0},{0,0,0,0},{0,0,0,0},{0,0,0,0}};
    f32x4 rsm[4] = {{0,0,0,0},{0,0,0,0},{0,0,0,0},{0,0,0,0}};
    f32x4 rsy[4] = {{0,0,0,0},{0,0,0,0},{0,0,0,0},{0,0,0,0}};

    stage(0, ms * 8);
    __syncthreads();

    for (int mt = 0; mt < 8; ++mt) {
        const int buf = mt & 1;
        if (mt < 7) stage(buf ^ 1, ms * 8 + mt + 1);

        f32x4 acc[4][4] = {{{0,0,0,0},{0,0,0,0},{0,0,0,0},{0,0,0,0}},
                           {{0,0,0,0},{0,0,0,0},{0,0,0,0},{0,0,0,0}},
                           {{0,0,0,0},{0,0,0,0},{0,0,0,0},{0,0,0,0}},
                           {{0,0,0,0},{0,0,0,0},{0,0,0,0},{0,0,0,0}}};
        const char* base = (const char*)&Bs[buf][0];
        #pragma unroll
        for (int kk = 0; kk < 4; ++kk) {
            #pragma unroll
            for (int msub = 0; msub < 4; ++msub) {
                const int byte = msub * 4096 + l15 * 256 +
                                 ((kk * 64 + g * 16) ^ ((l15 & 7) << 4));
                bf16x8 bfrag = *reinterpret_cast<const bf16x8*>(base + byte);
                #pragma unroll
                for (int s = 0; s < 4; ++s)
                    acc[s][msub] = __builtin_amdgcn_mfma_f32_16x16x32_bf16(
                        afrag[s][kk], bfrag, acc[s][msub], 0, 0, 0);
            }
        }
        const float y0 = (float)(ms * 8 + mt);   // m>>6 constant per aligned 64-tile
        #pragma unroll
        for (int s = 0; s < 4; ++s) {
            #pragma unroll
            for (int r = 0; r < 4; ++r) {
                float p0 = __expf(acc[s][0][r]);   // A pre-scaled by SCALE
                float p1 = __expf(acc[s][1][r]);
                float p2 = __expf(acc[s][2][r]);
                float p3 = __expf(acc[s][3][r]);
                float ts = (p0 + p1) + (p2 + p3);
                rl[s][r]  += ts;
                rsy[s][r] += y0 * ts;
                rsm[s][r] += fmaf(3.f, p3, fmaf(2.f, p2, p1));  // x = l15 + 16*msub
            }
        }
        __syncthreads();
    }

    const float xl = (float)l15;
    #pragma unroll
    for (int s = 0; s < 4; ++s) {
        #pragma unroll
        for (int r = 0; r < 4; ++r) {
            float a  = rl[s][r];
            float sx = xl * rl[s][r] + 16.f * rsm[s][r];
            float sy = rsy[s][r];
            #pragma unroll
            for (int m = 1; m < 16; m <<= 1) {
                a  += __shfl_xor(a, m);
                sx += __shfl_xor(sx, m);
                sy += __shfl_xor(sy, m);
            }
            if (l15 == 0) {
                const int n = n0 + s * 16 + g * 4 + r;
                part[((size_t)b * NHW + n) * 8 + ms] = make_float4(a, sx, sy, 0.f);
            }
        }
    }
}

// ---------------- finalize: combine 8 partials, emit flow ----------------
__global__ __launch_bounds__(256) void finalize_kernel(
        const float4* __restrict__ part, float* __restrict__ out) {
    const int idx = blockIdx.x * 256 + threadIdx.x;   // 0..16383 = b*4096+n
    if (idx >= NB * NHW) return;
    const int n = idx & (NHW - 1);
    const int b = idx >> 12;
    float l = 0.f, sx = 0.f, sy = 0.f;
    #pragma unroll
    for (int i = 0; i < 8; ++i) {
        float4 p = part[(size_t)idx * 8 + i];
        l += p.x; sx += p.y; sy += p.z;
    }
    const float inv = 1.0f / l;
    out[(size_t)b * 2 * NHW + n]       = sx * inv - (float)(n & 63);
    out[(size_t)b * 2 * NHW + NHW + n] = sy * inv - (float)(n >> 6);
}

extern "C" void kernel_launch(void* const* d_in, const int* in_sizes, int n_in,
                              void* d_out, int out_size, void* d_ws, size_t ws_size,
                              hipStream_t stream) {
    const float* f0 = (const float*)d_in[0];
    const float* f1 = (const float*)d_in[1];
    float* pos = (float*)d_ws;                               // 512 KB
    __hip_bfloat16* F0t = (__hip_bfloat16*)(pos + 131072);   // 4 MB
    __hip_bfloat16* Bt  = F0t + (size_t)NB * NHW * NC;       // 4 MB
    __hip_bfloat16* Ktw = Bt  + (size_t)NB * NHW * NC;       // 4 MB
    __hip_bfloat16* At  = Ktw + (size_t)16 * NC * 1024;      // 4 MB
    float4* part = (float4*)(At + (size_t)NB * NHW * NC);    // 2 MB
    float* out = (float*)d_out;

    pos_kernel<<<512, 256, 0, stream>>>(pos);
    pack_kernel<<<512, 256, 0, stream>>>(f0, f1, pos, F0t, Bt, Ktw);
    attn_mfma_kernel<<<256, 256, 0, stream>>>(F0t, Bt, Ktw, At);
    corr_part_kernel<<<512, 256, 0, stream>>>(At, Bt, part);
    finalize_kernel<<<64, 256, 0, stream>>>(part, out);
}